// Round 3
// baseline (27555.875 us; speedup 1.0000x reference)
//
#include <hip/hip_runtime.h>
#include <stdint.h>

// status: 0=UNK, 1=decided-ABS-unprocessed, 2=decided-DONE-unprocessed (seed/overflow), 3=claimed/processed
#define STK 48

static __device__ __forceinline__ unsigned long long packkey(float f, int v) {
    uint32_t u = __float_as_uint(f);
    u = (u & 0x80000000u) ? ~u : (u | 0x80000000u);
    return ((unsigned long long)u << 32) | (unsigned long long)(~(uint32_t)v);
}

// ---------------- build in-degree of "absorption" DAG ----------------
// 4 edges/thread, one row per 16 threads (K%4==0 path)
__global__ void k_build4(const int* __restrict__ neighs, const float* __restrict__ hier,
                         int* __restrict__ pred, long E4, int K) {
    long t = (long)blockIdx.x * blockDim.x + threadIdx.x;
    if (t >= E4) return;
    long e = t * 4;
    int u = (int)(e / K);
    unsigned long long ku = packkey(hier[u], u);
    int4 w4 = *(const int4*)(neighs + e);
    #pragma unroll
    for (int j = 0; j < 4; j++) {
        int w = (j == 0) ? w4.x : (j == 1) ? w4.y : (j == 2) ? w4.z : w4.w;
        if (w < 0) continue;
        unsigned long long kw = packkey(hier[w], w);
        if (ku > kw)
            __hip_atomic_fetch_add(&pred[w], 1, __ATOMIC_RELAXED, __HIP_MEMORY_SCOPE_AGENT);
    }
}
__global__ void k_build1(const int* __restrict__ neighs, const float* __restrict__ hier,
                         int* __restrict__ pred, long E, int K) {
    long e = (long)blockIdx.x * blockDim.x + threadIdx.x;
    if (e >= E) return;
    int w = neighs[e];
    if (w < 0) return;
    int u = (int)(e / K);
    if (packkey(hier[u], u) > packkey(hier[w], w))
        __hip_atomic_fetch_add(&pred[w], 1, __ATOMIC_RELAXED, __HIP_MEMORY_SCOPE_AGENT);
}

// ---------------- seed: stable snapshot of pred==0 ----------------
__global__ void k_seed(const int* __restrict__ pred, int* __restrict__ status, int V) {
    int v = blockIdx.x * blockDim.x + threadIdx.x;
    if (v >= V) return;
    if (pred[v] == 0) status[v] = 2;
}

// ---------------- push/continuation DFS processing (single lane) ----------------
__device__ void process_chain(int v0, int cen0,
                              const int* __restrict__ neighs, const float* __restrict__ hier,
                              unsigned long long* best, int* pred, int* status, int K) {
    unsigned stk[STK];
    int sp = 0;
    stk[sp++] = (unsigned)v0 | ((unsigned)cen0 << 31);
    while (sp > 0) {
        unsigned ent = stk[--sp];
        int v = (int)(ent & 0x7FFFFFFFu);
        bool cen = (ent >> 31) != 0;
        unsigned long long kv = packkey(hier[v], v);
        const int* row = neighs + (size_t)v * (size_t)K;
        if (cen) {
            // phase A: broadcast our key into lower-key neighbours
            for (int k = 0; k < K; k++) {
                int w = row[k];
                if (w < 0) continue;
                unsigned long long kw = packkey(hier[w], w);
                if (kv > kw) {
                    unsigned long long old = __hip_atomic_fetch_max(
                        &best[w], kv, __ATOMIC_RELAXED, __HIP_MEMORY_SCOPE_AGENT);
                    if (old == 0ull) {   // first absorber => w decided ABS now
                        int exp0 = 0;
                        if (sp < STK) {
                            if (__hip_atomic_compare_exchange_strong(
                                    &status[w], &exp0, 3, __ATOMIC_RELAXED, __ATOMIC_RELAXED,
                                    __HIP_MEMORY_SCOPE_AGENT))
                                stk[sp++] = (unsigned)w;           // ABS child
                        } else {
                            __hip_atomic_compare_exchange_strong(
                                &status[w], &exp0, 1, __ATOMIC_RELEASE, __ATOMIC_RELAXED,
                                __HIP_MEMORY_SCOPE_AGENT);          // leave for poller
                        }
                    }
                }
            }
            __threadfence();   // all our maxes land before any of our subs
        }
        // phase B: release lower-key out-edges
        for (int k = 0; k < K; k++) {
            int w = row[k];
            if (w < 0) continue;
            unsigned long long kw = packkey(hier[w], w);
            if (kv > kw) {
                if (__hip_atomic_fetch_add(&pred[w], -1, __ATOMIC_RELAXED,
                                           __HIP_MEMORY_SCOPE_AGENT) == 1) {
                    unsigned long long b = __hip_atomic_load(&best[w], __ATOMIC_RELAXED,
                                                             __HIP_MEMORY_SCOPE_AGENT);
                    if (b == 0ull) {
                        // unique center discovery (no maxes ever arrive here)
                        if (sp < STK) {
                            __hip_atomic_store(&status[w], 3, __ATOMIC_RELAXED,
                                               __HIP_MEMORY_SCOPE_AGENT);
                            stk[sp++] = (unsigned)w | 0x80000000u;  // CENTER child
                        } else {
                            __hip_atomic_store(&status[w], 2, __ATOMIC_RELEASE,
                                               __HIP_MEMORY_SCOPE_AGENT);
                        }
                    } else {
                        int exp0 = 0;
                        if (sp < STK) {
                            if (__hip_atomic_compare_exchange_strong(
                                    &status[w], &exp0, 3, __ATOMIC_RELAXED, __ATOMIC_RELAXED,
                                    __HIP_MEMORY_SCOPE_AGENT))
                                stk[sp++] = (unsigned)w;            // ABS child (max-lane lost race)
                        } else {
                            __hip_atomic_compare_exchange_strong(
                                &status[w], &exp0, 1, __ATOMIC_RELEASE, __ATOMIC_RELAXED,
                                __HIP_MEMORY_SCOPE_AGENT);
                        }
                    }
                }
            }
        }
    }
}

// ---------------- propagate: poll backstop + push fast path ----------------
__global__ __launch_bounds__(256, 4)
void k_propagate(const int* __restrict__ neighs, const float* __restrict__ hier,
                 unsigned long long* best, int* pred, int* status,
                 int V, int K, int nwaves) {
    const int gtid = blockIdx.x * blockDim.x + threadIdx.x;
    const int wv = gtid >> 6, lane = gtid & 63;
    const int G = (V + 63) >> 6;
    int gb[4];
    int ng = 0;
    for (int g = wv; g < G && ng < 4; g += nwaves) gb[ng++] = g << 6;
    unsigned pend = 0;
    for (int i = 0; i < ng; i++) if (gb[i] + lane < V) pend |= 1u << i;

    long sweeps = 0;
    while (__any(pend != 0)) {
        bool found = false;
        for (int i = 0; i < ng; i++) {
            if (!__any((pend >> i) & 1u)) continue;
            int v = gb[i] + lane;
            int st = 0;
            if ((pend >> i) & 1u)
                st = __hip_atomic_load(&status[v], __ATOMIC_RELAXED, __HIP_MEMORY_SCOPE_AGENT);
            if (st == 1 || st == 2) {
                int exp = st;
                if (__hip_atomic_compare_exchange_strong(&status[v], &exp, 3,
                        __ATOMIC_ACQUIRE, __ATOMIC_RELAXED, __HIP_MEMORY_SCOPE_AGENT)) {
                    int cen = 0;
                    if (st == 2) {
                        unsigned long long b = __hip_atomic_load(&best[v], __ATOMIC_RELAXED,
                                                                 __HIP_MEMORY_SCOPE_AGENT);
                        cen = (b == 0ull) ? 1 : 0;
                    }
                    process_chain(v, cen, neighs, hier, best, pred, status, K);
                }
                st = 3;
                found = true;
            }
            if (st == 3) pend &= ~(1u << i);
        }
        if (!found) {
            __builtin_amdgcn_s_sleep(16);
            if (++sweeps > 400000) break;   // safety net
        }
    }
}

// ---------------- compact centers per segment ----------------
__global__ void k_compact(const float* __restrict__ hier,
                          const unsigned long long* __restrict__ best,
                          const int* __restrict__ row_splits,
                          unsigned long long* __restrict__ segKeys,
                          int* __restrict__ segIds,
                          int* __restrict__ counters,
                          int V, int NSEG) {
    int v = blockIdx.x * blockDim.x + threadIdx.x;
    if (v >= V) return;
    if (best[v] != 0ull) return;            // center <=> never absorbed
    int s = 0;
    while (s + 1 < NSEG && v >= row_splits[s + 1]) s++;
    int p = atomicAdd(&counters[s], 1);
    int base = row_splits[s];
    segKeys[base + p] = packkey(hier[v], v);
    segIds[base + p]  = v;
}

// ---------------- rs prefix (tiny) ----------------
__global__ void k_rs(const int* __restrict__ counters,
                     int* __restrict__ rsBase,
                     int* __restrict__ rs_out,
                     int NSEG) {
    if (blockIdx.x == 0 && threadIdx.x == 0) {
        int acc = 0;
        rs_out[0] = 0;
        for (int s = 0; s < NSEG; s++) {
            rsBase[s] = acc;
            acc += counters[s];
            rs_out[s + 1] = acc;
        }
    }
}

// ---------------- rank centers -> cid, sel ----------------
__global__ void k_rank(const unsigned long long* __restrict__ segKeys,
                       const int* __restrict__ segIds,
                       const int* __restrict__ counters,
                       const int* __restrict__ rsBase,
                       const int* __restrict__ row_splits,
                       int* __restrict__ cidOf,
                       int* __restrict__ sel_out,
                       int V, int NSEG) {
    int t = blockIdx.x * blockDim.x + threadIdx.x;
    if (t >= V) return;
    int s = 0;
    while (s + 1 < NSEG && t >= row_splits[s + 1]) s++;
    int base = row_splits[s];
    int j = t - base;
    int cnt = counters[s];
    if (j >= cnt) return;
    unsigned long long mk = segKeys[t];
    int r = 0;
    for (int i = 0; i < cnt; i++) r += (segKeys[base + i] > mk) ? 1 : 0;
    int cid = rsBase[s] + r;
    int v = segIds[t];
    cidOf[v] = cid;
    sel_out[cid] = v;
}

// ---------------- final cluster assignment ----------------
__global__ void k_assign(const unsigned long long* __restrict__ best,
                         const int* __restrict__ cidOf,
                         int* __restrict__ clus_out,
                         int V) {
    int v = blockIdx.x * blockDim.x + threadIdx.x;
    if (v >= V) return;
    unsigned long long b = best[v];
    int c;
    if (b == 0ull) {
        c = cidOf[v];                                   // center
    } else {
        uint32_t a = ~(uint32_t)(b & 0xFFFFFFFFull);    // absorber global index
        c = cidOf[a];
    }
    clus_out[v] = c;
}

extern "C" void kernel_launch(void* const* d_in, const int* in_sizes, int n_in,
                              void* d_out, int out_size, void* d_ws, size_t ws_size,
                              hipStream_t stream) {
    const int*   neighs     = (const int*)d_in[0];
    const float* hier       = (const float*)d_in[1];
    const int*   row_splits = (const int*)d_in[2];

    const int V    = in_sizes[1];
    const int K    = in_sizes[0] / V;
    const int NSEG = in_sizes[2] - 1;
    const long E   = (long)V * (long)K;

    int* out      = (int*)d_out;
    int* sel_out  = out;
    int* rs_out   = out + V;
    int* clus_out = out + V + NSEG + 1;

    // workspace layout: [best 8V][pred 4V][status 4V][counters 256B][segKeys 8V][segIds 4V][cidOf 4V]
    char* w = (char*)d_ws;
    unsigned long long* best    = (unsigned long long*)(w);
    int* pred     = (int*)(w + (size_t)8  * V);
    int* status   = (int*)(w + (size_t)12 * V);
    int* counters = (int*)(w + (size_t)16 * V);
    unsigned long long* segKeys = (unsigned long long*)(w + (size_t)16 * V + 256);
    int* segIds   = (int*)(w + (size_t)24 * V + 256);
    int* cidOf    = (int*)(w + (size_t)28 * V + 256);

    const int B  = 256;
    const int gV = (V + B - 1) / B;

    hipMemsetAsync(w, 0, (size_t)16 * V + 256, stream);        // best, pred, status, counters
    hipMemsetAsync(sel_out, 0xFF, (size_t)4 * V, stream);      // sel padded with -1

    if ((K & 3) == 0) {
        long E4 = E / 4;
        k_build4<<<(int)((E4 + B - 1) / B), B, 0, stream>>>(neighs, hier, pred, E4, K);
    } else {
        k_build1<<<(int)((E + B - 1) / B), B, 0, stream>>>(neighs, hier, pred, E, K);
    }
    k_seed<<<gV, B, 0, stream>>>(pred, status, V);

    const int PB = 1024;                  // 4 blocks/CU co-resident
    const int NW = PB * B / 64;           // 4096 waves
    k_propagate<<<PB, B, 0, stream>>>(neighs, hier, best, pred, status, V, K, NW);

    k_compact<<<gV, B, 0, stream>>>(hier, best, row_splits, segKeys, segIds, counters, V, NSEG);
    k_rs<<<1, 64, 0, stream>>>(counters, counters + 16, rs_out, NSEG);
    k_rank<<<gV, B, 0, stream>>>(segKeys, segIds, counters, counters + 16, row_splits,
                                 cidOf, sel_out, V, NSEG);
    k_assign<<<gV, B, 0, stream>>>(best, cidOf, clus_out, V);
}

// Round 6
// 2871.387 us; speedup vs baseline: 9.5967x; 9.5967x over previous
//
#include <hip/hip_runtime.h>
#include <stdint.h>

typedef unsigned long long ull;

static __device__ __forceinline__ ull packkey(float f, int v) {
    uint32_t u = __float_as_uint(f);
    u = (u & 0x80000000u) ? ~u : (u | 0x80000000u);
    return ((ull)u << 32) | (ull)(~(uint32_t)v);
}

// ---------------- build in-degree of "absorption" DAG (fire-and-forget adds) ----------------
__global__ void k_build4(const int* __restrict__ neighs, const float* __restrict__ hier,
                         int* __restrict__ pred, long E4, int K) {
    long t = (long)blockIdx.x * blockDim.x + threadIdx.x;
    if (t >= E4) return;
    long e = t * 4;
    int u = (int)(e / K);
    ull ku = packkey(hier[u], u);
    int4 w4 = *(const int4*)(neighs + e);
    int ws[4] = {w4.x, w4.y, w4.z, w4.w};
    #pragma unroll
    for (int j = 0; j < 4; j++) {
        int w = ws[j];
        if (w < 0) continue;
        if (ku > packkey(hier[w], w))
            __hip_atomic_fetch_add(&pred[w], 1, __ATOMIC_RELAXED, __HIP_MEMORY_SCOPE_AGENT);
    }
}
__global__ void k_build1(const int* __restrict__ neighs, const float* __restrict__ hier,
                         int* __restrict__ pred, long E, int K) {
    long e = (long)blockIdx.x * blockDim.x + threadIdx.x;
    if (e >= E) return;
    int w = neighs[e];
    if (w < 0) return;
    int u = (int)(e / K);
    if (packkey(hier[u], u) > packkey(hier[w], w))
        __hip_atomic_fetch_add(&pred[w], 1, __ATOMIC_RELAXED, __HIP_MEMORY_SCOPE_AGENT);
}

// ---------------- propagation: owner polls pred/best; fire-and-forget updates ----------------
// Decision rules (owner-side, no status array):
//   ABS    : best[v] != 0  (first absorber's max landed; process immediately, don't wait pred)
//   CENTER : pred[v] == 0 and best[v] == 0 re-verified after pred observation
//            (sound: every in-neighbor fences its maxes before its subs, so pred==0
//             implies all center in-neighbors' maxes have landed => best is final)
static __device__ __forceinline__ bool sweep_group(
    int gb, bool pend, int lane,
    const int* __restrict__ neighs, const float* __restrict__ hier,
    ull* __restrict__ best, int* __restrict__ pred, int K, bool& found)
{
    if (!__any(pend)) return pend;
    int v = gb + lane;
    ull b = 0; int p = 1;
    if (pend) {
        b = __hip_atomic_load(&best[v], __ATOMIC_RELAXED, __HIP_MEMORY_SCOPE_AGENT);
        p = __hip_atomic_load(&pred[v], __ATOMIC_RELAXED, __HIP_MEMORY_SCOPE_AGENT);
    }
    bool absn = pend && (b != 0ull);
    bool cenm = pend && (b == 0ull) && (p == 0);
    bool cenn = false;
    if (__any(cenm)) {
        __threadfence();   // acquire: order the best re-read after the pred observation
        ull b2 = 0;
        if (cenm) b2 = __hip_atomic_load(&best[v], __ATOMIC_RELAXED, __HIP_MEMORY_SCOPE_AGENT);
        cenn = cenm && (b2 == 0ull);
    }
    bool dec = absn || cenn;
    uint64_t mdec = __ballot(dec);
    if (!mdec) return pend;
    found = true;
    uint64_t mcen = __ballot(cenn);

    while (mdec) {
        int ls[4];
        int nb = 0;
        while (nb < 4 && mdec) {
            int l = __ffsll((unsigned long long)mdec) - 1;
            mdec &= mdec - 1;
            ls[nb++] = l;
        }
        #pragma unroll
        for (int j = nb; j < 4; j++) ls[j] = -1;

        int vv[4]; ull kv[4]; bool cj[4]; bool anyc = false;
        #pragma unroll
        for (int j = 0; j < 4; j++) {
            vv[j] = 0; kv[j] = 0; cj[j] = false;
            if (ls[j] >= 0) {
                vv[j] = gb + ls[j];
                cj[j] = (mcen >> ls[j]) & 1ull;
                anyc |= cj[j];
                kv[j] = packkey(hier[vv[j]], vv[j]);
            }
        }
        // phase A: centers broadcast their key into lower-key out-neighbours (no return)
        if (__any(anyc)) {
            for (int k0 = 0; k0 < K; k0 += 64) {
                int k = k0 + lane;
                bool kok = k < K;
                #pragma unroll
                for (int j = 0; j < 4; j++) {
                    if (ls[j] >= 0 && cj[j] && kok) {
                        int w = neighs[(size_t)vv[j] * (size_t)K + k];
                        if (w >= 0 && kv[j] > packkey(hier[w], w))
                            __hip_atomic_fetch_max(&best[w], kv[j],
                                                   __ATOMIC_RELAXED, __HIP_MEMORY_SCOPE_AGENT);
                    }
                }
            }
            __threadfence();   // all our maxes land before any of our subs
        }
        // phase B: every decided vertex releases its lower-key out-edges (no return)
        for (int k0 = 0; k0 < K; k0 += 64) {
            int k = k0 + lane;
            bool kok = k < K;
            #pragma unroll
            for (int j = 0; j < 4; j++) {
                if (ls[j] >= 0 && kok) {
                    int w = neighs[(size_t)vv[j] * (size_t)K + k];
                    if (w >= 0 && kv[j] > packkey(hier[w], w))
                        __hip_atomic_fetch_add(&pred[w], -1,
                                               __ATOMIC_RELAXED, __HIP_MEMORY_SCOPE_AGENT);
                }
            }
        }
    }
    return pend && !dec;
}

__global__ __launch_bounds__(256, 4)
void k_propagate(const int* __restrict__ neighs, const float* __restrict__ hier,
                 ull* __restrict__ best, int* __restrict__ pred,
                 int V, int K, int nwaves) {
    const int gtid = blockIdx.x * blockDim.x + threadIdx.x;
    const int wv = gtid >> 6, lane = gtid & 63;
    const int G = (V + 63) >> 6;
    int gb0 = -1, gb1 = -1, gb2 = -1, gb3 = -1;
    {
        int g = wv;
        if (g < G) { gb0 = g << 6; g += nwaves; }
        if (g < G) { gb1 = g << 6; g += nwaves; }
        if (g < G) { gb2 = g << 6; g += nwaves; }
        if (g < G) { gb3 = g << 6; }
    }
    bool p0 = gb0 >= 0 && gb0 + lane < V;
    bool p1 = gb1 >= 0 && gb1 + lane < V;
    bool p2 = gb2 >= 0 && gb2 + lane < V;
    bool p3 = gb3 >= 0 && gb3 + lane < V;

    long sweeps = 0;
    while (__any(p0 || p1 || p2 || p3)) {
        bool found = false;
        p0 = sweep_group(gb0, p0, lane, neighs, hier, best, pred, K, found);
        p1 = sweep_group(gb1, p1, lane, neighs, hier, best, pred, K, found);
        p2 = sweep_group(gb2, p2, lane, neighs, hier, best, pred, K, found);
        p3 = sweep_group(gb3, p3, lane, neighs, hier, best, pred, K, found);
        if (!found) {
            __builtin_amdgcn_s_sleep(2);
            if (++sweeps > 150000L) break;   // safety net: never hang the bench
        }
    }
}

// ---------------- compact centers per segment ----------------
__global__ void k_compact(const float* __restrict__ hier,
                          const ull* __restrict__ best,
                          const int* __restrict__ row_splits,
                          ull* __restrict__ segKeys,
                          int* __restrict__ segIds,
                          int* __restrict__ counters,
                          int V, int NSEG) {
    int v = blockIdx.x * blockDim.x + threadIdx.x;
    if (v >= V) return;
    if (best[v] != 0ull) return;            // center <=> never absorbed
    int s = 0;
    while (s + 1 < NSEG && v >= row_splits[s + 1]) s++;
    int p = atomicAdd(&counters[s], 1);
    int base = row_splits[s];
    segKeys[base + p] = packkey(hier[v], v);
    segIds[base + p]  = v;
}

// ---------------- rs prefix (tiny) ----------------
__global__ void k_rs(const int* __restrict__ counters,
                     int* __restrict__ rsBase,
                     int* __restrict__ rs_out,
                     int NSEG) {
    if (blockIdx.x == 0 && threadIdx.x == 0) {
        int acc = 0;
        rs_out[0] = 0;
        for (int s = 0; s < NSEG; s++) {
            rsBase[s] = acc;
            acc += counters[s];
            rs_out[s + 1] = acc;
        }
    }
}

// ---------------- rank centers -> cid, sel ----------------
__global__ void k_rank(const ull* __restrict__ segKeys,
                       const int* __restrict__ segIds,
                       const int* __restrict__ counters,
                       const int* __restrict__ rsBase,
                       const int* __restrict__ row_splits,
                       int* __restrict__ cidOf,
                       int* __restrict__ sel_out,
                       int V, int NSEG) {
    int t = blockIdx.x * blockDim.x + threadIdx.x;
    if (t >= V) return;
    int s = 0;
    while (s + 1 < NSEG && t >= row_splits[s + 1]) s++;
    int base = row_splits[s];
    int j = t - base;
    int cnt = counters[s];
    if (j >= cnt) return;
    ull mk = segKeys[t];
    int r = 0;
    for (int i = 0; i < cnt; i++) r += (segKeys[base + i] > mk) ? 1 : 0;
    int cid = rsBase[s] + r;
    int v = segIds[t];
    cidOf[v] = cid;
    sel_out[cid] = v;
}

// ---------------- final cluster assignment ----------------
__global__ void k_assign(const ull* __restrict__ best,
                         const int* __restrict__ cidOf,
                         int* __restrict__ clus_out,
                         int V) {
    int v = blockIdx.x * blockDim.x + threadIdx.x;
    if (v >= V) return;
    ull b = best[v];
    int c;
    if (b == 0ull) {
        c = cidOf[v];                                   // center
    } else {
        uint32_t a = ~(uint32_t)(b & 0xFFFFFFFFull);    // absorber global index
        c = cidOf[a];
    }
    clus_out[v] = c;
}

extern "C" void kernel_launch(void* const* d_in, const int* in_sizes, int n_in,
                              void* d_out, int out_size, void* d_ws, size_t ws_size,
                              hipStream_t stream) {
    const int*   neighs     = (const int*)d_in[0];
    const float* hier       = (const float*)d_in[1];
    const int*   row_splits = (const int*)d_in[2];

    const int V    = in_sizes[1];
    const int K    = in_sizes[0] / V;
    const int NSEG = in_sizes[2] - 1;
    const long E   = (long)V * (long)K;

    int* out      = (int*)d_out;
    int* sel_out  = out;
    int* rs_out   = out + V;
    int* clus_out = out + V + NSEG + 1;

    // workspace: [best 8V][pred 4V][counters 256B][segKeys 8V][segIds 4V][cidOf 4V] = 28V+256
    char* w = (char*)d_ws;
    ull* best     = (ull*)(w);
    int* pred     = (int*)(w + (size_t)8  * V);
    int* counters = (int*)(w + (size_t)12 * V);
    ull* segKeys  = (ull*)(w + (size_t)12 * V + 256);
    int* segIds   = (int*)(w + (size_t)20 * V + 256);
    int* cidOf    = (int*)(w + (size_t)24 * V + 256);

    const int B  = 256;
    const int gV = (V + B - 1) / B;

    (void)hipMemsetAsync(w, 0, (size_t)12 * V + 256, stream);     // best, pred, counters
    (void)hipMemsetAsync(sel_out, 0xFF, (size_t)4 * V, stream);   // sel padded with -1

    if ((K & 3) == 0) {
        long E4 = E / 4;
        k_build4<<<(int)((E4 + B - 1) / B), B, 0, stream>>>(neighs, hier, pred, E4, K);
    } else {
        k_build1<<<(int)((E + B - 1) / B), B, 0, stream>>>(neighs, hier, pred, E, K);
    }

    const int PB = 1024;                  // 4 blocks/CU co-resident (<=128 VGPR @ (256,4))
    const int NW = PB * B / 64;           // 4096 waves
    k_propagate<<<PB, B, 0, stream>>>(neighs, hier, best, pred, V, K, NW);

    k_compact<<<gV, B, 0, stream>>>(hier, best, row_splits, segKeys, segIds, counters, V, NSEG);
    k_rs<<<1, 64, 0, stream>>>(counters, counters + 16, rs_out, NSEG);
    k_rank<<<gV, B, 0, stream>>>(segKeys, segIds, counters, counters + 16, row_splits,
                                 cidOf, sel_out, V, NSEG);
    k_assign<<<gV, B, 0, stream>>>(best, cidOf, clus_out, V);
}